// Round 8
// baseline (357.809 us; speedup 1.0000x reference)
//
#include <hip/hip_runtime.h>
#include <hip/hip_bf16.h>
#include <cstddef>
#include <cstdint>

#define B_ 32
#define T_ 2048
#define D_ 512
#define U_ 512

typedef __attribute__((ext_vector_type(8))) short bf16x8;   // 8 bf16 = 4 VGPRs
typedef __attribute__((ext_vector_type(4))) float f32x4;    // MFMA 16x16 accum

__device__ __forceinline__ unsigned short f2bf(float f) {
  union { float f; unsigned u; } x; x.f = f;
  unsigned r = x.u + 0x7fffu + ((x.u >> 16) & 1u);  // RNE
  return (unsigned short)(r >> 16);
}
__device__ __forceinline__ float tanh_fast(float x) {
  float e = __expf(2.0f * x);
  return 1.0f - 2.0f * __builtin_amdgcn_rcpf(e + 1.0f);
}

// C = sum |Vw| : tanh-bound => |score| <= C, so exp(s-C) in (0,1] -- softmax needs no
// global max pass. Computed IDENTICALLY (wave-0 only, fixed shfl order) in k2attn and
// kB_final => bit-identical C in both kernels.
__device__ __forceinline__ void wave0_sumabs_vw(const float* __restrict__ Vw,
                                                float* Cs, int tid) {
  if (tid < 64) {
    float c = 0.f;
    #pragma unroll
    for (int i = 0; i < 8; ++i) c += fabsf(Vw[tid + i * 64]);
    c += __shfl_xor(c, 1);  c += __shfl_xor(c, 2);  c += __shfl_xor(c, 4);
    c += __shfl_xor(c, 8);  c += __shfl_xor(c, 16); c += __shfl_xor(c, 32);
    if (tid == 0) *Cs = c;
  }
}

// ---------- kA: W2 pack (blocks 0..63) + q_proj/ctx-zero (64..319) ---------- [R5-verified]
__global__ void kA_prep(const float* __restrict__ W2, unsigned* __restrict__ W2P,
                        const float* __restrict__ query, const float* __restrict__ W1,
                        const float* __restrict__ W1b, const float* __restrict__ W2b,
                        float* __restrict__ qp, float* __restrict__ ctx) {
  const int tid = threadIdx.x;              // 256
  if (blockIdx.x < 64) {
    const int kg = blockIdx.x >> 2, q4 = blockIdx.x & 3;  // 8 k-rows: kg*32+q4*8 ..+7
    __shared__ unsigned short w2s[8][514];
    const float4* W2v = (const float4*)(W2 + (size_t)(kg * 32 + q4 * 8) * U_);
    #pragma unroll
    for (int i = 0; i < 4; ++i) {
      int idx4 = i * 256 + tid;             // float4 index in 8x512 slab (128 per row)
      float4 v = W2v[idx4];
      int r = idx4 >> 7, c = (idx4 & 127) * 4;
      w2s[r][c + 0] = f2bf(v.x); w2s[r][c + 1] = f2bf(v.y);
      w2s[r][c + 2] = f2bf(v.z); w2s[r][c + 3] = f2bf(v.w);
    }
    __syncthreads();
    const int idx = tid & 63;
    const int lr = (idx >> 2) & 15, j = idx & 3;
    const int kb = j * 2;                   // local row within the 8-row slab
    #pragma unroll
    for (int r = 0; r < 8; ++r) {
      int ut = r * 4 + (tid >> 6);
      W2P[ut * 4096 + kg * 256 + q4 * 64 + idx] =
          (unsigned)w2s[kb][ut * 16 + lr] | ((unsigned)w2s[kb + 1][ut * 16 + lr] << 16);
    }
  } else {
    // qproj: 256 blocks = 32 b x 8 u-slices(64). 4-way d-split per u + LDS reduce.
    __shared__ float qs[D_];
    __shared__ float red[4][64];
    const int blk2 = blockIdx.x - 64;       // 0..255
    const int b = blk2 >> 3, us = blk2 & 7;
    const int ul = tid & 63, dq = tid >> 6; // u-local, d-quarter
    const int u = us * 64 + ul;
    qs[tid] = query[b * D_ + tid];
    qs[tid + 256] = query[b * D_ + tid + 256];
    __syncthreads();
    float a0 = 0, a1 = 0, a2 = 0, a3 = 0;
    const int d0 = dq * 128;
    for (int d = 0; d < 128; d += 4) {
      a0 += qs[d0 + d + 0] * W1[(size_t)(d0 + d + 0) * U_ + u];
      a1 += qs[d0 + d + 1] * W1[(size_t)(d0 + d + 1) * U_ + u];
      a2 += qs[d0 + d + 2] * W1[(size_t)(d0 + d + 2) * U_ + u];
      a3 += qs[d0 + d + 3] * W1[(size_t)(d0 + d + 3) * U_ + u];
    }
    red[dq][ul] = (a0 + a1) + (a2 + a3);
    __syncthreads();
    if (dq == 0) {
      float s = red[0][ul] + red[1][ul] + red[2][ul] + red[3][ul];
      qp[b * U_ + u] = s + W1b[u] + W2b[u];
    }
    if (tid < 64) ctx[blk2 * 64 + tid] = 0.0f;  // 256*64 = 16384: zero unnormalized ctx
  }
}

// lane fragment: 8 fp32 at base+kg*32 (k = kg*32 + lq*8 ..+7) -> bf16x8
#define LOADA(dst, base)                                                  \
  { f32x4 flo = *(const f32x4*)((base) + kg * 32);                        \
    f32x4 fhi = *(const f32x4*)((base) + kg * 32 + 4);                    \
    union { bf16x8 v; __hip_bfloat162 h[4]; } Au;                         \
    Au.h[0] = __float22bfloat162_rn(make_float2(flo.x, flo.y));           \
    Au.h[1] = __float22bfloat162_rn(make_float2(flo.z, flo.w));           \
    Au.h[2] = __float22bfloat162_rn(make_float2(fhi.x, fhi.y));           \
    Au.h[3] = __float22bfloat162_rn(make_float2(fhi.z, fhi.w));           \
    dst = Au.v; }

// ---------- k2attn v9: BARRIER-FREE K-loop -- A direct from global (no LDS staging) ----------
// R7 confirmed the 4x4-acc wave geometry (85us); its residual is (1) __syncthreads draining
// vmcnt(0) every eighth (all 8 waves eat worst-case HBM latency 8x/block) and (2) 8x-redundant
// A fragment read+cvt (a[mi] is wave-independent). v9 deletes the mechanism: each lane loads
// its A fragment (32B: rows mi*16+lr, k=kg*32+lq*8) straight from values. K-loop has ZERO
// barriers -> waves free-run and de-phase (m114 MFMA/VALU overlap), compiler pipelines the
// fully-unrolled 16-kg loop with no fences. A-reads are 16-row-strided but every byte of each
// line is consumed across kg -> HBM fetch unchanged; redundancy (~512KB/block) is L1/L2-served
// (~20 TB/s demand < 34.5 TB/s L2 ceiling -- the stated risk, falsifiable via flat dur).
// B: per-kg quad loads, no manual double-buffer (no barriers to defeat; compiler hoists).
// Geometry: 1024 blocks x 512 thr (8 waves), wave w owns u-group w*4..w*4+3, 4x4 acc.
// Epilogue verbatim from R7 (harness-verified, absmax 4.9e-4).
__global__ __launch_bounds__(512, 4) void k2attn(
    const float* __restrict__ values, const unsigned short* __restrict__ W2P,
    const float* __restrict__ qp, const float* __restrict__ Vw,
    float* __restrict__ score, float* __restrict__ ctxU) {
  __shared__ float sred[8][64];
  __shared__ float ps2[64];
  __shared__ float Cs;

  const int tid = threadIdx.x;              // 512
  const int bx = blockIdx.x;                // 1024 = 32 chunks x 32 batches
  const int m0 = bx * 64;                   // flat row (b*2048 + t); never crosses batch
  const int b = m0 >> 11;
  const int l = tid & 63, w = tid >> 6;     // 8 waves; wave w owns u-tiles w*4..w*4+3
  const int lr = l & 15, lq = l >> 4;

  f32x4 acc[4][4];                          // 4x4 fragment tile (R7-verified geometry)
  #pragma unroll
  for (int mi = 0; mi < 4; ++mi)
    #pragma unroll
    for (int ni = 0; ni < 4; ++ni) acc[mi][ni] = (f32x4){0.f, 0.f, 0.f, 0.f};

  const unsigned short* Bb = W2P + (size_t)(w * 4) * 8192 + (size_t)l * 8;
  const float* a0p = values + (size_t)(m0 + lr) * D_ + lq * 8;   // mi=0 row base
  const float* a1p = a0p + (size_t)16 * D_;
  const float* a2p = a0p + (size_t)32 * D_;
  const float* a3p = a0p + (size_t)48 * D_;

  wave0_sumabs_vw(Vw, &Cs, tid);

  #pragma unroll
  for (int kg = 0; kg < 16; ++kg) {         // K = 512 = 16 x K32; no barriers anywhere
    bf16x8 Bv[4];
    #pragma unroll
    for (int ni = 0; ni < 4; ++ni)
      Bv[ni] = *(const bf16x8*)(Bb + (size_t)ni * 8192 + (size_t)kg * 512);
    bf16x8 af0, af1, af2, af3;
    LOADA(af0, a0p); LOADA(af1, a1p); LOADA(af2, a2p); LOADA(af3, a3p);
    #pragma unroll
    for (int ni = 0; ni < 4; ++ni) {
      acc[0][ni] = __builtin_amdgcn_mfma_f32_16x16x32_bf16(af0, Bv[ni], acc[0][ni], 0, 0, 0);
      acc[1][ni] = __builtin_amdgcn_mfma_f32_16x16x32_bf16(af1, Bv[ni], acc[1][ni], 0, 0, 0);
      acc[2][ni] = __builtin_amdgcn_mfma_f32_16x16x32_bf16(af2, Bv[ni], acc[2][ni], 0, 0, 0);
      acc[3][ni] = __builtin_amdgcn_mfma_f32_16x16x32_bf16(af3, Bv[ni], acc[3][ni], 0, 0, 0);
    }
  }

  // ---- epilogue 1: tanh + Vw-weighted reduce over u (C/D: col=lr -> u, row=lq*4+r) ----
  float sacc[4][4];
  #pragma unroll
  for (int mi = 0; mi < 4; ++mi)
    #pragma unroll
    for (int r = 0; r < 4; ++r) sacc[mi][r] = 0.0f;
  #pragma unroll
  for (int ni = 0; ni < 4; ++ni) {
    int u = (w * 4 + ni) * 16 + lr;
    float qpv = qp[b * U_ + u], vv = Vw[u];
    #pragma unroll
    for (int mi = 0; mi < 4; ++mi)
      #pragma unroll
      for (int r = 0; r < 4; ++r)
        sacc[mi][r] += tanh_fast(acc[mi][ni][r] + qpv) * vv;
  }
  #pragma unroll
  for (int mi = 0; mi < 4; ++mi)
    #pragma unroll
    for (int r = 0; r < 4; ++r) {
      float v = sacc[mi][r];
      v += __shfl_xor(v, 1); v += __shfl_xor(v, 2);
      v += __shfl_xor(v, 4); v += __shfl_xor(v, 8);
      if (lr == 0) sred[w][mi * 16 + lq * 4 + r] = v;
    }
  __syncthreads();

  // ---- epilogue 2: raw scores + p = exp(s - C) ----
  if (tid < 64) {
    float s = 0.f;
    #pragma unroll
    for (int wv = 0; wv < 8; ++wv) s += sred[wv][tid];
    score[m0 + tid] = s;                    // raw score (kB normalizes in place)
    ps2[tid] = __expf(s - Cs);
  }
  __syncthreads();

  // ---- epilogue 3: unnormalized context from L2-warm values rows ----
  float accc = 0.f;
  const int col = tid;                      // 512 threads <-> 512 cols
  #pragma unroll 4
  for (int row = 0; row < 64; ++row)
    accc += ps2[row] * values[(size_t)(m0 + row) * D_ + col];
  atomicAdd(&ctxU[(size_t)b * D_ + col], accc);
}

// ---------- kB: normalize (replaces softmax + ctx kernels) ---------- [R3-verified]
__global__ void kB_final(const float* __restrict__ Vw, float* __restrict__ attn,
                         float* __restrict__ ctx) {
  __shared__ float Cs;
  __shared__ float red[4];
  const int b = blockIdx.x, tid = threadIdx.x;  // 32 blocks x 256
  wave0_sumabs_vw(Vw, &Cs, tid);
  __syncthreads();
  const float C = Cs;
  float* s = attn + b * T_;
  float p[8];
  float sum = 0.f;
  #pragma unroll
  for (int i = 0; i < 8; ++i) { p[i] = __expf(s[tid + i * 256] - C); sum += p[i]; }
  #pragma unroll
  for (int off = 1; off < 64; off <<= 1) sum += __shfl_xor(sum, off);
  if ((tid & 63) == 0) red[tid >> 6] = sum;
  __syncthreads();
  sum = (red[0] + red[1]) + (red[2] + red[3]);
  const float inv = 1.0f / sum;
  #pragma unroll
  for (int i = 0; i < 8; ++i) attn[b * T_ + tid + i * 256] = p[i] * inv;
  #pragma unroll
  for (int i = 0; i < 2; ++i) ctx[b * D_ + tid + i * 256] *= inv;
}

extern "C" void kernel_launch(void* const* d_in, const int* in_sizes, int n_in,
                              void* d_out, int out_size, void* d_ws, size_t ws_size,
                              hipStream_t stream) {
  const float* query = (const float*)d_in[0];
  const float* values = (const float*)d_in[1];
  const float* W1w = (const float*)d_in[2];
  const float* W1b = (const float*)d_in[3];
  const float* W2w = (const float*)d_in[4];
  const float* W2b = (const float*)d_in[5];
  const float* Vw  = (const float*)d_in[6];
  // V_b (d_in[7]) is a constant shift under softmax -> dropped.

  float* out = (float*)d_out;
  float* ctx  = out;                 // [B, D]: unnormalized ctx until kB scales in place
  float* attn = out + B_ * D_;       // [B, T, 1]: raw scores until kB softmaxes in place
  float* score = attn;

  char* ws = (char*)d_ws;            // needs 576 KB (unchanged)
  unsigned* W2P = (unsigned*)ws;                             // 512 KB packed bf16 B
  float* qp    = (float*)(ws + 512 * 1024);                  // 64 KB

  kA_prep<<<320, 256, 0, stream>>>(W2w, W2P, query, W1w, W1b, W2b, qp, ctx);
  k2attn<<<1024, 512, 0, stream>>>(values, (const unsigned short*)W2P, qp, Vw, score, ctx);
  kB_final<<<32, 256, 0, stream>>>(Vw, attn, ctx);
}

// Round 9
// 266.895 us; speedup vs baseline: 1.3406x; 1.3406x over previous
//
#include <hip/hip_runtime.h>
#include <hip/hip_bf16.h>
#include <cstddef>
#include <cstdint>

#define B_ 32
#define T_ 2048
#define D_ 512
#define U_ 512

typedef __attribute__((ext_vector_type(8))) short bf16x8;   // 8 bf16 = 4 VGPRs
typedef __attribute__((ext_vector_type(4))) float f32x4;    // MFMA 16x16 accum

__device__ __forceinline__ unsigned short f2bf(float f) {
  union { float f; unsigned u; } x; x.f = f;
  unsigned r = x.u + 0x7fffu + ((x.u >> 16) & 1u);  // RNE
  return (unsigned short)(r >> 16);
}
__device__ __forceinline__ float tanh_fast(float x) {
  float e = __expf(2.0f * x);
  return 1.0f - 2.0f * __builtin_amdgcn_rcpf(e + 1.0f);
}
__device__ __forceinline__ unsigned packbf2(float a, float b) {
  union { __hip_bfloat162 h; unsigned u; } c;
  c.h = __float22bfloat162_rn(make_float2(a, b));
  return c.u;
}

// C = sum |Vw| : tanh-bound => |score| <= C, so exp(s-C) in (0,1] -- softmax needs no
// global max pass. Computed IDENTICALLY (wave-0 only, fixed shfl order) in k2attn and
// kB_final => bit-identical C in both kernels.
__device__ __forceinline__ void wave0_sumabs_vw(const float* __restrict__ Vw,
                                                float* Cs, int tid) {
  if (tid < 64) {
    float c = 0.f;
    #pragma unroll
    for (int i = 0; i < 8; ++i) c += fabsf(Vw[tid + i * 64]);
    c += __shfl_xor(c, 1);  c += __shfl_xor(c, 2);  c += __shfl_xor(c, 4);
    c += __shfl_xor(c, 8);  c += __shfl_xor(c, 16); c += __shfl_xor(c, 32);
    if (tid == 0) *Cs = c;
  }
}

// ---------- kA: W2 pack (blocks 0..63) + q_proj/ctx-zero (64..319) ---------- [R5-verified]
__global__ void kA_prep(const float* __restrict__ W2, unsigned* __restrict__ W2P,
                        const float* __restrict__ query, const float* __restrict__ W1,
                        const float* __restrict__ W1b, const float* __restrict__ W2b,
                        float* __restrict__ qp, float* __restrict__ ctx) {
  const int tid = threadIdx.x;              // 256
  if (blockIdx.x < 64) {
    const int kg = blockIdx.x >> 2, q4 = blockIdx.x & 3;  // 8 k-rows: kg*32+q4*8 ..+7
    __shared__ unsigned short w2s[8][514];
    const float4* W2v = (const float4*)(W2 + (size_t)(kg * 32 + q4 * 8) * U_);
    #pragma unroll
    for (int i = 0; i < 4; ++i) {
      int idx4 = i * 256 + tid;             // float4 index in 8x512 slab (128 per row)
      float4 v = W2v[idx4];
      int r = idx4 >> 7, c = (idx4 & 127) * 4;
      w2s[r][c + 0] = f2bf(v.x); w2s[r][c + 1] = f2bf(v.y);
      w2s[r][c + 2] = f2bf(v.z); w2s[r][c + 3] = f2bf(v.w);
    }
    __syncthreads();
    const int idx = tid & 63;
    const int lr = (idx >> 2) & 15, j = idx & 3;
    const int kb = j * 2;                   // local row within the 8-row slab
    #pragma unroll
    for (int r = 0; r < 8; ++r) {
      int ut = r * 4 + (tid >> 6);
      W2P[ut * 4096 + kg * 256 + q4 * 64 + idx] =
          (unsigned)w2s[kb][ut * 16 + lr] | ((unsigned)w2s[kb + 1][ut * 16 + lr] << 16);
    }
  } else {
    // qproj: 256 blocks = 32 b x 8 u-slices(64). 4-way d-split per u + LDS reduce.
    __shared__ float qs[D_];
    __shared__ float red[4][64];
    const int blk2 = blockIdx.x - 64;       // 0..255
    const int b = blk2 >> 3, us = blk2 & 7;
    const int ul = tid & 63, dq = tid >> 6; // u-local, d-quarter
    const int u = us * 64 + ul;
    qs[tid] = query[b * D_ + tid];
    qs[tid + 256] = query[b * D_ + tid + 256];
    __syncthreads();
    float a0 = 0, a1 = 0, a2 = 0, a3 = 0;
    const int d0 = dq * 128;
    for (int d = 0; d < 128; d += 4) {
      a0 += qs[d0 + d + 0] * W1[(size_t)(d0 + d + 0) * U_ + u];
      a1 += qs[d0 + d + 1] * W1[(size_t)(d0 + d + 1) * U_ + u];
      a2 += qs[d0 + d + 2] * W1[(size_t)(d0 + d + 2) * U_ + u];
      a3 += qs[d0 + d + 3] * W1[(size_t)(d0 + d + 3) * U_ + u];
    }
    red[dq][ul] = (a0 + a1) + (a2 + a3);
    __syncthreads();
    if (dq == 0) {
      float s = red[0][ul] + red[1][ul] + red[2][ul] + red[3][ul];
      qp[b * U_ + u] = s + W1b[u] + W2b[u];
    }
    if (tid < 64) ctx[blk2 * 64 + tid] = 0.0f;  // 256*64 = 16384: zero unnormalized ctx
  }
}

// ---------- k2attn v10: R7 geometry + BF16 reg-staged A (cvt once, not 8x) ----------
// R7 (84.5us, verified): fp32 DMA staging; VALUBusy 30% dominated by 8x-redundant per-wave
// fragment cvt (256 cvt_pk/lane). v10 stages A as BF16 via T14 reg-staging: global->reg ->
// cvt ONCE -> swizzled ds_write_b128. Per-lane cvt 256->32; ds_read bytes halved (4 b128/kg).
// v9 lesson applied: __launch_bounds__(512,3) (<=170 regs incl 64 AGPR acc) -- no spill.
// Buffers: quarter tiles [64 rows][128 k] bf16 = 16 KB x2 (double-buffered). ONE barrier
// per quarter (4 total): loads for q+2 issued FIRST after the barrier (full quarter of MFMA
// covers HBM latency before the next barrier's vmcnt drain); write of q+1 happens after
// compute(q) -- its buffer's previous readers all passed the preceding barrier (audited).
// Swizzle: 16-slot XOR  phys = s ^ (row&15)  on 256B rows, bijective both sides; same
// bank-minimal structure as R7 (measured 0 conflicts). Operand order matches R7 verbatim
// (slot s holds k = s*8..s*8+7 in order). Geometry/epilogue: R7 verbatim (4x4 acc, 8 waves,
// fused score+exp+ctx epilogue; absmax 4.9e-4 expected bit-identical).
__global__ __launch_bounds__(512, 3) void k2attn(
    const float* __restrict__ values, const unsigned short* __restrict__ W2P,
    const float* __restrict__ qp, const float* __restrict__ Vw,
    float* __restrict__ score, float* __restrict__ ctxU) {
  __shared__ __align__(16) unsigned short av[2][64][128];   // 2 x 16 KB bf16 quarter tiles
  __shared__ float sred[8][64];
  __shared__ float ps2[64];
  __shared__ float Cs;

  const int tid = threadIdx.x;              // 512
  const int bx = blockIdx.x;                // 1024 = 32 chunks x 32 batches
  const int m0 = bx * 64;                   // flat row (b*2048 + t); never crosses batch
  const int b = m0 >> 11;
  const int l = tid & 63, w = tid >> 6;     // 8 waves; wave w owns u-tiles w*4..w*4+3
  const int lr = l & 15, lq = l >> 4;

  // staging role: thread t owns row r_st = t>>3, slots s0 = (t&7)*2 and s0+1
  // (slot s covers k = s*8 .. s*8+7 of the quarter; 16 floats = 4 x float4 per quarter)
  const int r_st = tid >> 3;
  const int s0 = (tid & 7) * 2;
  const int r15 = r_st & 15;
  const float* gsrc = values + (size_t)(m0 + r_st) * D_ + s0 * 8;
  char* wd0 = (char*)&av[0][r_st][0] + ((s0 ^ r15) << 4);
  char* wd1 = (char*)&av[0][r_st][0] + (((s0 + 1) ^ r15) << 4);

  f32x4 acc[4][4];                          // 4x4 fragment tile (R7-verified geometry)
  #pragma unroll
  for (int mi = 0; mi < 4; ++mi)
    #pragma unroll
    for (int ni = 0; ni < 4; ++ni) acc[mi][ni] = (f32x4){0.f, 0.f, 0.f, 0.f};

  const unsigned short* Bb = W2P + (size_t)(w * 4) * 8192 + (size_t)l * 8;

  float4 La[4], Lb[4];
  auto loadG = [&](float4* L, int q) {
    const float4* g = (const float4*)(gsrc + q * 128);
    L[0] = g[0]; L[1] = g[1]; L[2] = g[2]; L[3] = g[3];
  };
  auto writeL = [&](int p, const float4* L) {   // cvt once + 2 swizzled ds_write_b128
    uint4 w0 = make_uint4(packbf2(L[0].x, L[0].y), packbf2(L[0].z, L[0].w),
                          packbf2(L[1].x, L[1].y), packbf2(L[1].z, L[1].w));
    uint4 w1 = make_uint4(packbf2(L[2].x, L[2].y), packbf2(L[2].z, L[2].w),
                          packbf2(L[3].x, L[3].y), packbf2(L[3].z, L[3].w));
    *(uint4*)(wd0 + p * 16384) = w0;
    *(uint4*)(wd1 + p * 16384) = w1;
  };

  wave0_sumabs_vw(Vw, &Cs, tid);

  // prologue: buf0 <- q0; issue q1 loads (drained once at this barrier -- one-time cost)
  loadG(La, 0);
  writeL(0, La);
  loadG(Lb, 1);
  __syncthreads();                          // buf0 ready + Cs published

  bf16x8 Bc[4], Bn[4];
  #pragma unroll
  for (int ni = 0; ni < 4; ++ni) Bc[ni] = *(const bf16x8*)(Bb + (size_t)ni * 8192);

  #pragma unroll
  for (int q = 0; q < 4; ++q) {             // K = 512 = 4 quarters x (4 x K32)
    const int p = q & 1;
    if (q == 0) loadG(La, 2);               // issued first after barrier: quarter of
    else if (q == 1) loadG(Lb, 3);          // compute covers latency before next drain
    const char* buf = (const char*)av[p];
    #pragma unroll
    for (int kgl = 0; kgl < 4; ++kgl) {
      const int kg = q * 4 + kgl;
      if (kg < 15) {
        #pragma unroll
        for (int ni = 0; ni < 4; ++ni)
          Bn[ni] = *(const bf16x8*)(Bb + (size_t)ni * 8192 + (size_t)(kg + 1) * 512);
      }
      bf16x8 a[4];
      #pragma unroll
      for (int mi = 0; mi < 4; ++mi) {
        const int row = mi * 16 + lr;       // row&15 == lr
        const int phys = (kgl * 4 + lq) ^ lr;
        a[mi] = *(const bf16x8*)(buf + row * 256 + (phys << 4));
      }
      #pragma unroll
      for (int ni = 0; ni < 4; ++ni)
        #pragma unroll
        for (int mi = 0; mi < 4; ++mi)
          acc[mi][ni] = __builtin_amdgcn_mfma_f32_16x16x32_bf16(a[mi], Bc[ni], acc[mi][ni], 0, 0, 0);
      #pragma unroll
      for (int ni = 0; ni < 4; ++ni) Bc[ni] = Bn[ni];
    }
    if (q < 3) {
      writeL(p ^ 1, (q & 1) ? La : Lb);     // q1/q3 data from Lb; q2 from La (static names)
      __syncthreads();                      // next buf ready; prev readers provably done
    }
  }

  // ---- epilogue 1: tanh + Vw-weighted reduce over u (C/D: col=lr -> u, row=lq*4+r) ----
  float sacc[4][4];
  #pragma unroll
  for (int mi = 0; mi < 4; ++mi)
    #pragma unroll
    for (int r = 0; r < 4; ++r) sacc[mi][r] = 0.0f;
  #pragma unroll
  for (int ni = 0; ni < 4; ++ni) {
    int u = (w * 4 + ni) * 16 + lr;
    float qpv = qp[b * U_ + u], vv = Vw[u];
    #pragma unroll
    for (int mi = 0; mi < 4; ++mi)
      #pragma unroll
      for (int r = 0; r < 4; ++r)
        sacc[mi][r] += tanh_fast(acc[mi][ni][r] + qpv) * vv;
  }
  #pragma unroll
  for (int mi = 0; mi < 4; ++mi)
    #pragma unroll
    for (int r = 0; r < 4; ++r) {
      float v = sacc[mi][r];
      v += __shfl_xor(v, 1); v += __shfl_xor(v, 2);
      v += __shfl_xor(v, 4); v += __shfl_xor(v, 8);
      if (lr == 0) sred[w][mi * 16 + lq * 4 + r] = v;
    }
  __syncthreads();

  // ---- epilogue 2: raw scores + p = exp(s - C) ----
  if (tid < 64) {
    float s = 0.f;
    #pragma unroll
    for (int wv = 0; wv < 8; ++wv) s += sred[wv][tid];
    score[m0 + tid] = s;                    // raw score (kB normalizes in place)
    ps2[tid] = __expf(s - Cs);
  }
  __syncthreads();

  // ---- epilogue 3: unnormalized context from L2-warm values rows ----
  float accc = 0.f;
  const int col = tid;                      // 512 threads <-> 512 cols
  #pragma unroll 4
  for (int row = 0; row < 64; ++row)
    accc += ps2[row] * values[(size_t)(m0 + row) * D_ + col];
  atomicAdd(&ctxU[(size_t)b * D_ + col], accc);
}

// ---------- kB: normalize (replaces softmax + ctx kernels) ---------- [R3-verified]
__global__ void kB_final(const float* __restrict__ Vw, float* __restrict__ attn,
                         float* __restrict__ ctx) {
  __shared__ float Cs;
  __shared__ float red[4];
  const int b = blockIdx.x, tid = threadIdx.x;  // 32 blocks x 256
  wave0_sumabs_vw(Vw, &Cs, tid);
  __syncthreads();
  const float C = Cs;
  float* s = attn + b * T_;
  float p[8];
  float sum = 0.f;
  #pragma unroll
  for (int i = 0; i < 8; ++i) { p[i] = __expf(s[tid + i * 256] - C); sum += p[i]; }
  #pragma unroll
  for (int off = 1; off < 64; off <<= 1) sum += __shfl_xor(sum, off);
  if ((tid & 63) == 0) red[tid >> 6] = sum;
  __syncthreads();
  sum = (red[0] + red[1]) + (red[2] + red[3]);
  const float inv = 1.0f / sum;
  #pragma unroll
  for (int i = 0; i < 8; ++i) attn[b * T_ + tid + i * 256] = p[i] * inv;
  #pragma unroll
  for (int i = 0; i < 2; ++i) ctx[b * D_ + tid + i * 256] *= inv;
}

extern "C" void kernel_launch(void* const* d_in, const int* in_sizes, int n_in,
                              void* d_out, int out_size, void* d_ws, size_t ws_size,
                              hipStream_t stream) {
  const float* query = (const float*)d_in[0];
  const float* values = (const float*)d_in[1];
  const float* W1w = (const float*)d_in[2];
  const float* W1b = (const float*)d_in[3];
  const float* W2w = (const float*)d_in[4];
  const float* W2b = (const float*)d_in[5];
  const float* Vw  = (const float*)d_in[6];
  // V_b (d_in[7]) is a constant shift under softmax -> dropped.

  float* out = (float*)d_out;
  float* ctx  = out;                 // [B, D]: unnormalized ctx until kB scales in place
  float* attn = out + B_ * D_;       // [B, T, 1]: raw scores until kB softmaxes in place
  float* score = attn;

  char* ws = (char*)d_ws;            // needs 576 KB (unchanged)
  unsigned* W2P = (unsigned*)ws;                             // 512 KB packed bf16 B
  float* qp    = (float*)(ws + 512 * 1024);                  // 64 KB

  kA_prep<<<320, 256, 0, stream>>>(W2w, W2P, query, W1w, W1b, W2b, qp, ctx);
  k2attn<<<1024, 512, 0, stream>>>(values, (const unsigned short*)W2P, qp, Vw, score, ctx);
  kB_final<<<32, 256, 0, stream>>>(Vw, attn, ctx);
}

// Round 10
// 242.303 us; speedup vs baseline: 1.4767x; 1.1015x over previous
//
#include <hip/hip_runtime.h>
#include <hip/hip_bf16.h>
#include <cstddef>
#include <cstdint>

#define B_ 32
#define T_ 2048
#define D_ 512
#define U_ 512

typedef __attribute__((ext_vector_type(8))) short bf16x8;   // 8 bf16 = 4 VGPRs
typedef __attribute__((ext_vector_type(4))) float f32x4;    // MFMA 16x16 accum

__device__ __forceinline__ unsigned short f2bf(float f) {
  union { float f; unsigned u; } x; x.f = f;
  unsigned r = x.u + 0x7fffu + ((x.u >> 16) & 1u);  // RNE
  return (unsigned short)(r >> 16);
}
__device__ __forceinline__ float tanh_fast(float x) {
  float e = __expf(2.0f * x);
  return 1.0f - 2.0f * __builtin_amdgcn_rcpf(e + 1.0f);
}

#define AS1C(p) ((const __attribute__((address_space(1))) unsigned*)(p))
#define AS3(p)  ((__attribute__((address_space(3))) unsigned*)(p))

// C = sum |Vw| : tanh-bound => |score| <= C, so exp(s-C) in (0,1] -- softmax needs no
// global max pass. Computed IDENTICALLY (wave-0 only, fixed shfl order) in k2attn and
// kB_final => bit-identical C in both kernels.
__device__ __forceinline__ void wave0_sumabs_vw(const float* __restrict__ Vw,
                                                float* Cs, int tid) {
  if (tid < 64) {
    float c = 0.f;
    #pragma unroll
    for (int i = 0; i < 8; ++i) c += fabsf(Vw[tid + i * 64]);
    c += __shfl_xor(c, 1);  c += __shfl_xor(c, 2);  c += __shfl_xor(c, 4);
    c += __shfl_xor(c, 8);  c += __shfl_xor(c, 16); c += __shfl_xor(c, 32);
    if (tid == 0) *Cs = c;
  }
}

// ---------- kA: W2 pack (blocks 0..63) + q_proj/ctx-zero (64..319) ---------- [R5-verified]
__global__ void kA_prep(const float* __restrict__ W2, unsigned* __restrict__ W2P,
                        const float* __restrict__ query, const float* __restrict__ W1,
                        const float* __restrict__ W1b, const float* __restrict__ W2b,
                        float* __restrict__ qp, float* __restrict__ ctx) {
  const int tid = threadIdx.x;              // 256
  if (blockIdx.x < 64) {
    const int kg = blockIdx.x >> 2, q4 = blockIdx.x & 3;  // 8 k-rows: kg*32+q4*8 ..+7
    __shared__ unsigned short w2s[8][514];
    const float4* W2v = (const float4*)(W2 + (size_t)(kg * 32 + q4 * 8) * U_);
    #pragma unroll
    for (int i = 0; i < 4; ++i) {
      int idx4 = i * 256 + tid;             // float4 index in 8x512 slab (128 per row)
      float4 v = W2v[idx4];
      int r = idx4 >> 7, c = (idx4 & 127) * 4;
      w2s[r][c + 0] = f2bf(v.x); w2s[r][c + 1] = f2bf(v.y);
      w2s[r][c + 2] = f2bf(v.z); w2s[r][c + 3] = f2bf(v.w);
    }
    __syncthreads();
    const int idx = tid & 63;
    const int lr = (idx >> 2) & 15, j = idx & 3;
    const int kb = j * 2;                   // local row within the 8-row slab
    #pragma unroll
    for (int r = 0; r < 8; ++r) {
      int ut = r * 4 + (tid >> 6);
      W2P[ut * 4096 + kg * 256 + q4 * 64 + idx] =
          (unsigned)w2s[kb][ut * 16 + lr] | ((unsigned)w2s[kb + 1][ut * 16 + lr] << 16);
    }
  } else {
    // qproj: 256 blocks = 32 b x 8 u-slices(64). 4-way d-split per u + LDS reduce.
    __shared__ float qs[D_];
    __shared__ float red[4][64];
    const int blk2 = blockIdx.x - 64;       // 0..255
    const int b = blk2 >> 3, us = blk2 & 7;
    const int ul = tid & 63, dq = tid >> 6; // u-local, d-quarter
    const int u = us * 64 + ul;
    qs[tid] = query[b * D_ + tid];
    qs[tid + 256] = query[b * D_ + tid + 256];
    __syncthreads();
    float a0 = 0, a1 = 0, a2 = 0, a3 = 0;
    const int d0 = dq * 128;
    for (int d = 0; d < 128; d += 4) {
      a0 += qs[d0 + d + 0] * W1[(size_t)(d0 + d + 0) * U_ + u];
      a1 += qs[d0 + d + 1] * W1[(size_t)(d0 + d + 1) * U_ + u];
      a2 += qs[d0 + d + 2] * W1[(size_t)(d0 + d + 2) * U_ + u];
      a3 += qs[d0 + d + 3] * W1[(size_t)(d0 + d + 3) * U_ + u];
    }
    red[dq][ul] = (a0 + a1) + (a2 + a3);
    __syncthreads();
    if (dq == 0) {
      float s = red[0][ul] + red[1][ul] + red[2][ul] + red[3][ul];
      qp[b * U_ + u] = s + W1b[u] + W2b[u];
    }
    if (tid < 64) ctx[blk2 * 64 + tid] = 0.0f;  // 256*64 = 16384: zero unnormalized ctx
  }
}

// ---------- k2attn v8 (RESTORED R7 optimum): 4x4-acc waves + DMA staging + fused epilogue ----
// Verified 84.5us / e2e 241.6us (R7). Session evidence for why each piece is load-bearing:
//   * 4x4 acc fragment tile (64 AGPR): 2x4 variants = +25% time (R3/R6).
//   * 64 arch VGPR + 64 AGPR = exactly 128 -> 2 blocks/CU (R9: 148 regs -> 1 block, +40%;
//     R8: bounds-forced 128 -> scratch spill, +140%). NO reg-staging fits this geometry.
//   * global_load_lds DMA staging (0 staging regs, 0 SQ-LDS write conflicts; R9's
//     reg-staged ds_write_b128 = 524K conflicts).
//   * plain __syncthreads per eighth; NO fences/setprio/counted-vmcnt (m141; R1/R5 null:
//     kernel is memory-latency-insensitive -- hot-L3 replays run identical 84us).
//   * full-U block -> fused score+exp+ctx epilogue (eliminates k3/k4, -23us e2e vs R0).
// Occupancy pins at ~41% across ALL configs tried; per-wave efficiency is the only lever
// and this point maximizes it. Structural ceiling documented R0-R9.
__global__ __launch_bounds__(512, 4) void k2attn(
    const float* __restrict__ values, const unsigned short* __restrict__ W2P,
    const float* __restrict__ qp, const float* __restrict__ Vw,
    float* __restrict__ score, float* __restrict__ ctxU) {
  __shared__ __align__(16) float av[2][4096];   // 2 x 16 KB fp32 A buffers (64 rows x 64 f)
  __shared__ float sred[8][64];
  __shared__ float ps2[64];
  __shared__ float Cs;

  const int tid = threadIdx.x;              // 512
  const int bx = blockIdx.x;                // 1024 = 32 chunks x 32 batches
  const int m0 = bx * 64;                   // flat row (b*2048 + t); never crosses batch
  const int b = m0 >> 11;
  const int l = tid & 63, w = tid >> 6;     // 8 waves; wave w owns u-tiles w*4..w*4+3
  const int lr = l & 15, lq = l >> 4;

  // staging: thread t covers rows r0=t>>4 and r0+32; source chunk (t&15)^(row&15)
  const int r0 = tid >> 4;
  const int c0 = tid & 15;
  const float* vsrc0 = values + (size_t)(m0 + r0) * D_ + (c0 ^ (r0 & 15)) * 4;
  const float* vsrc1 = values + (size_t)(m0 + 32 + r0) * D_ + (c0 ^ (r0 & 15)) * 4;

  f32x4 acc[4][4];                          // R0's 4x4 fragment tile (64 acc regs)
  #pragma unroll
  for (int mi = 0; mi < 4; ++mi)
    #pragma unroll
    for (int ni = 0; ni < 4; ++ni) acc[mi][ni] = (f32x4){0.f, 0.f, 0.f, 0.f};

  const unsigned short* Bb = W2P + (size_t)(w * 4) * 8192 + (size_t)l * 8;

  auto stage = [&](int e, int p) {          // DMA eighth e into buffer p (2 instr/thread)
    __builtin_amdgcn_global_load_lds(AS1C(vsrc0 + e * 64), AS3(&av[p][(r0) * 64 + ((tid & 15) << 2)]), 16, 0, 0);
    __builtin_amdgcn_global_load_lds(AS1C(vsrc1 + e * 64), AS3(&av[p][(32 + r0) * 64 + ((tid & 15) << 2)]), 16, 0, 0);
  };

  wave0_sumabs_vw(Vw, &Cs, tid);

  bf16x8 Bc[4], Bn[4];
  stage(0, 0);
  #pragma unroll
  for (int ni = 0; ni < 4; ++ni) Bc[ni] = *(const bf16x8*)(Bb + (size_t)ni * 8192);

  for (int kg = 0; kg < 16; ++kg) {         // K = 512 = 16 x K32
    const int e = kg >> 1, p = e & 1;
    if ((kg & 1) == 0) {
      __syncthreads();                      // drains DMA(e) (a full eighth in flight)
      if (e < 7) stage(e + 1, p ^ 1);       // overlaps compute of kg, kg+1
    }
    if (kg < 15) {
      #pragma unroll
      for (int ni = 0; ni < 4; ++ni)
        Bn[ni] = *(const bf16x8*)(Bb + (size_t)ni * 8192 + (size_t)(kg + 1) * 512);
    }
    const int kq = kg & 1;
    const int p0 = (kq * 8 + lq * 2) ^ lr;  // swizzled position of chunk pair
    bf16x8 a[4];
    #pragma unroll
    for (int mi = 0; mi < 4; ++mi) {
      const int row = mi * 16 + lr;
      f32x4 flo = *(const f32x4*)&av[p][row * 64 + (p0 << 2)];
      f32x4 fhi = *(const f32x4*)&av[p][row * 64 + ((p0 ^ 1) << 2)];
      union { bf16x8 v; __hip_bfloat162 h[4]; } A;
      A.h[0] = __float22bfloat162_rn(make_float2(flo.x, flo.y));
      A.h[1] = __float22bfloat162_rn(make_float2(flo.z, flo.w));
      A.h[2] = __float22bfloat162_rn(make_float2(fhi.x, fhi.y));
      A.h[3] = __float22bfloat162_rn(make_float2(fhi.z, fhi.w));
      a[mi] = A.v;
    }
    #pragma unroll
    for (int ni = 0; ni < 4; ++ni)
      #pragma unroll
      for (int mi = 0; mi < 4; ++mi)
        acc[mi][ni] = __builtin_amdgcn_mfma_f32_16x16x32_bf16(a[mi], Bc[ni], acc[mi][ni], 0, 0, 0);
    #pragma unroll
    for (int ni = 0; ni < 4; ++ni) Bc[ni] = Bn[ni];
  }

  // ---- epilogue 1: tanh + Vw-weighted reduce over u (C/D: col=lr -> u, row=lq*4+r) ----
  float sacc[4][4];
  #pragma unroll
  for (int mi = 0; mi < 4; ++mi)
    #pragma unroll
    for (int r = 0; r < 4; ++r) sacc[mi][r] = 0.0f;
  #pragma unroll
  for (int ni = 0; ni < 4; ++ni) {
    int u = (w * 4 + ni) * 16 + lr;
    float qpv = qp[b * U_ + u], vv = Vw[u];
    #pragma unroll
    for (int mi = 0; mi < 4; ++mi)
      #pragma unroll
      for (int r = 0; r < 4; ++r)
        sacc[mi][r] += tanh_fast(acc[mi][ni][r] + qpv) * vv;
  }
  #pragma unroll
  for (int mi = 0; mi < 4; ++mi)
    #pragma unroll
    for (int r = 0; r < 4; ++r) {
      float v = sacc[mi][r];
      v += __shfl_xor(v, 1); v += __shfl_xor(v, 2);
      v += __shfl_xor(v, 4); v += __shfl_xor(v, 8);
      if (lr == 0) sred[w][mi * 16 + lq * 4 + r] = v;
    }
  __syncthreads();

  // ---- epilogue 2: raw scores + p = exp(s - C) ----
  if (tid < 64) {
    float s = 0.f;
    #pragma unroll
    for (int wv = 0; wv < 8; ++wv) s += sred[wv][tid];
    score[m0 + tid] = s;                    // raw score (kB normalizes in place)
    ps2[tid] = __expf(s - Cs);
  }
  __syncthreads();

  // ---- epilogue 3: unnormalized context from L2-warm values rows ----
  float accc = 0.f;
  const int col = tid;                      // 512 threads <-> 512 cols
  #pragma unroll 4
  for (int row = 0; row < 64; ++row)
    accc += ps2[row] * values[(size_t)(m0 + row) * D_ + col];
  atomicAdd(&ctxU[(size_t)b * D_ + col], accc);
}

// ---------- kB: normalize (replaces softmax + ctx kernels) ---------- [R3-verified]
__global__ void kB_final(const float* __restrict__ Vw, float* __restrict__ attn,
                         float* __restrict__ ctx) {
  __shared__ float Cs;
  __shared__ float red[4];
  const int b = blockIdx.x, tid = threadIdx.x;  // 32 blocks x 256
  wave0_sumabs_vw(Vw, &Cs, tid);
  __syncthreads();
  const float C = Cs;
  float* s = attn + b * T_;
  float p[8];
  float sum = 0.f;
  #pragma unroll
  for (int i = 0; i < 8; ++i) { p[i] = __expf(s[tid + i * 256] - C); sum += p[i]; }
  #pragma unroll
  for (int off = 1; off < 64; off <<= 1) sum += __shfl_xor(sum, off);
  if ((tid & 63) == 0) red[tid >> 6] = sum;
  __syncthreads();
  sum = (red[0] + red[1]) + (red[2] + red[3]);
  const float inv = 1.0f / sum;
  #pragma unroll
  for (int i = 0; i < 8; ++i) attn[b * T_ + tid + i * 256] = p[i] * inv;
  #pragma unroll
  for (int i = 0; i < 2; ++i) ctx[b * D_ + tid + i * 256] *= inv;
}

extern "C" void kernel_launch(void* const* d_in, const int* in_sizes, int n_in,
                              void* d_out, int out_size, void* d_ws, size_t ws_size,
                              hipStream_t stream) {
  const float* query = (const float*)d_in[0];
  const float* values = (const float*)d_in[1];
  const float* W1w = (const float*)d_in[2];
  const float* W1b = (const float*)d_in[3];
  const float* W2w = (const float*)d_in[4];
  const float* W2b = (const float*)d_in[5];
  const float* Vw  = (const float*)d_in[6];
  // V_b (d_in[7]) is a constant shift under softmax -> dropped.

  float* out = (float*)d_out;
  float* ctx  = out;                 // [B, D]: unnormalized ctx until kB scales in place
  float* attn = out + B_ * D_;       // [B, T, 1]: raw scores until kB softmaxes in place
  float* score = attn;

  char* ws = (char*)d_ws;            // needs 576 KB (unchanged)
  unsigned* W2P = (unsigned*)ws;                             // 512 KB packed bf16 B
  float* qp    = (float*)(ws + 512 * 1024);                  // 64 KB

  kA_prep<<<320, 256, 0, stream>>>(W2w, W2P, query, W1w, W1b, W2b, qp, ctx);
  k2attn<<<1024, 512, 0, stream>>>(values, (const unsigned short*)W2P, qp, Vw, score, ctx);
  kB_final<<<32, 256, 0, stream>>>(Vw, attn, ctx);
}